// Round 6
// baseline (908.863 us; speedup 1.0000x reference)
//
#include <hip/hip_runtime.h>
#include <cstddef>

#define T_SEQ 11
#define STEPS 80

typedef _Float16 f16;
typedef _Float16 f16x4 __attribute__((ext_vector_type(4)));
typedef _Float16 f16x8 __attribute__((ext_vector_type(8)));
typedef float    f32x4 __attribute__((ext_vector_type(4)));

__device__ __forceinline__ f32x4 mfma16(f16x8 a, f16x8 b, f32x4 c) {
    return __builtin_amdgcn_mfma_f32_16x16x32_f16(a, b, c, 0, 0, 0);
}
__device__ __forceinline__ float sig1(float x) {
    return __fdividef(1.f, 1.f + __expf(-x));
}
__device__ __forceinline__ float th1(float x) {
    return 1.f - __fdividef(2.f, __expf(2.f * x) + 1.f);
}

// A-frag: lane holds W[row][k0..k0+7] (m = lane&15 selects row within tile).
__device__ __forceinline__ f16x8 wfrag(const float* __restrict__ W, int row, int k0) {
    f16x8 r;
    #pragma unroll
    for (int i = 0; i < 8; ++i) r[i] = (f16)W[row * 64 + k0 + i];
    return r;
}
// Composed decoder-l0 gi weights: Wcomb[g][k] = Wih0[g][0]*fcW[0][k] + Wih0[g][1]*fcW[1][k]
__device__ __forceinline__ f16x8 cfrag(const float* __restrict__ Wih0,
                                       const float* __restrict__ fcW, int row, int k0) {
    f16x8 r;
    #pragma unroll
    for (int i = 0; i < 8; ++i)
        r[i] = (f16)(Wih0[row * 2] * fcW[k0 + i] + Wih0[row * 2 + 1] * fcW[64 + k0 + i]);
    return r;
}

struct WSet {
    f16x8 xR[2], xZ[2], xN[2];   // gi-source weights (MFMA path)
    f16x8 hR[2], hZ[2], hN[2];   // recurrent weights
    f32x4 bR, bZ, bNi, bNh;      // biases, vector over rg (j = j4+rg)
};

__device__ __forceinline__ void load_h_side(WSet& W,
    const float* __restrict__ Whh, const float* __restrict__ bih,
    const float* __restrict__ bhh, int jA, int j4, int quad)
{
    #pragma unroll
    for (int ks = 0; ks < 2; ++ks) {
        const int k0 = ks * 32 + quad * 8;
        W.hR[ks] = wfrag(Whh, jA,       k0);
        W.hZ[ks] = wfrag(Whh, jA + 64,  k0);
        W.hN[ks] = wfrag(Whh, jA + 128, k0);
    }
    #pragma unroll
    for (int rg = 0; rg < 4; ++rg) {
        W.bR[rg]  = bih[j4 + rg] + bhh[j4 + rg];
        W.bZ[rg]  = bih[64 + j4 + rg] + bhh[64 + j4 + rg];
        W.bNi[rg] = bih[128 + j4 + rg];
        W.bNh[rg] = bhh[128 + j4 + rg];
    }
}
__device__ __forceinline__ void load_x_side(WSet& W, const float* __restrict__ Wx,
                                            int jA, int quad)
{
    #pragma unroll
    for (int ks = 0; ks < 2; ++ks) {
        const int k0 = ks * 32 + quad * 8;
        W.xR[ks] = wfrag(Wx, jA,       k0);
        W.xZ[ks] = wfrag(Wx, jA + 64,  k0);
        W.xN[ks] = wfrag(Wx, jA + 128, k0);
    }
}

// One GRU cell, D[j][row] orientation. Reads B-frags (h) from swizzled LDS,
// writes new h (f16x4 per row-tile) to Dst. hreg keeps the fp32 h master copy.
template<bool XM>
__device__ __forceinline__ void cell(const WSet& W,
    const f16* __restrict__ Xs, const f16* __restrict__ Hs, f16* __restrict__ Dst,
    float (&hreg)[16], const f32x4* __restrict__ xw, const float2* __restrict__ xv,
    int ro0, int ro1, int wo)
{
    #pragma unroll
    for (int mt = 0; mt < 4; ++mt) {
        f32x4 aR = W.bR, aZ = W.bZ, aNi = W.bNi, aNh = W.bNh;
        const int mo = mt * 1024;
        f16x8 hb0 = *(const f16x8*)(Hs + ro0 + mo);
        f16x8 hb1 = *(const f16x8*)(Hs + ro1 + mo);
        aR  = mfma16(W.hR[0], hb0, aR);  aR  = mfma16(W.hR[1], hb1, aR);
        aZ  = mfma16(W.hZ[0], hb0, aZ);  aZ  = mfma16(W.hZ[1], hb1, aZ);
        aNh = mfma16(W.hN[0], hb0, aNh); aNh = mfma16(W.hN[1], hb1, aNh);
        if constexpr (XM) {
            f16x8 xb0 = *(const f16x8*)(Xs + ro0 + mo);
            f16x8 xb1 = *(const f16x8*)(Xs + ro1 + mo);
            aR  = mfma16(W.xR[0], xb0, aR);  aR  = mfma16(W.xR[1], xb1, aR);
            aZ  = mfma16(W.xZ[0], xb0, aZ);  aZ  = mfma16(W.xZ[1], xb1, aZ);
            aNi = mfma16(W.xN[0], xb0, aNi); aNi = mfma16(W.xN[1], xb1, aNi);
        } else {
            const float x0 = xv[mt].x, x1 = xv[mt].y;
            aR  += x0 * xw[0] + x1 * xw[1];
            aZ  += x0 * xw[2] + x1 * xw[3];
            aNi += x0 * xw[4] + x1 * xw[5];
        }
        f16x4 o;
        #pragma unroll
        for (int i = 0; i < 4; ++i) {
            const float r = sig1(aR[i]);
            const float z = sig1(aZ[i]);
            const float n = th1(aNi[i] + r * aNh[i]);
            const float ho = hreg[mt * 4 + i];
            const float hn = n + z * (ho - n);
            hreg[mt * 4 + i] = hn;
            o[i] = (f16)hn;
        }
        *(f16x4*)(Dst + wo + mo) = o;   // one ds_write_b64, swizzle-aligned
    }
}

// launch_bounds(256,1): round-5 spilled ~49MB/dispatch to scratch at (256,2)
// (WRITE_SIZE 70MB vs 21MB output). Persistent state ~230 regs needs the full
// unified file; 1 wave/SIMD is fine for a VALU-issue-bound kernel with 4-way ILP.
__global__ __launch_bounds__(256, 1)
void gru_traj_mfma3(
    const float* __restrict__ x,
    const float* __restrict__ eWih0, const float* __restrict__ eWhh0,
    const float* __restrict__ ebih0, const float* __restrict__ ebhh0,
    const float* __restrict__ eWih1, const float* __restrict__ eWhh1,
    const float* __restrict__ ebih1, const float* __restrict__ ebhh1,
    const float* __restrict__ dWih0, const float* __restrict__ dWhh0,
    const float* __restrict__ dbih0, const float* __restrict__ dbhh0,
    const float* __restrict__ dWih1, const float* __restrict__ dWhh1,
    const float* __restrict__ dbih1, const float* __restrict__ dbhh1,
    const float* __restrict__ fcW,  const float* __restrict__ fcb,
    float* __restrict__ out)
{
    // 4 h buffers (double-buffered per layer), XOR-swizzled, no padding.
    __shared__ f16 hbuf[4][64 * 64];     // [0,1]=h0, [2,3]=h1
    __shared__ float2 xe[T_SEQ * 64];    // [t][row] -> 4-quad broadcast reads, conflict-free

    const int tid  = threadIdx.x;
    const int lane = tid & 63;
    const int w    = __builtin_amdgcn_readfirstlane(tid >> 6);
    const int quad = lane >> 4;
    const int col  = lane & 15;
    const int r0   = blockIdx.x * 64;

    for (int i = tid; i < T_SEQ * 64; i += 256) {
        const int t = i >> 6, r = i & 63;
        xe[i] = ((const float2*)x)[(size_t)(r0 + r) * T_SEQ + t];
    }
    for (int i = tid; i < 64 * 64; i += 256) { hbuf[0][i] = (f16)0.f; hbuf[2][i] = (f16)0.f; }

    // Swizzled offsets (halves): phys(row,k) = row*64 + (((k>>3)^(row&7))<<3) + (k&7)
    const int c7  = col & 7;
    const int ro0 = col * 64 + ((quad ^ c7) << 3);             // B-frag read, ks=0
    const int ro1 = col * 64 + (((4 + quad) ^ c7) << 3);       // B-frag read, ks=1
    const int wo  = col * 64 + ((((w << 1) | (quad >> 1)) ^ c7) << 3) + ((quad & 1) << 2);

    const int jA = w * 16 + col;        // A-frag W-row base (m = col)
    const int j4 = w * 16 + quad * 4;   // epilogue/bias j base (m = quad*4+rg)

    float hreg0[16], hreg1[16];
    #pragma unroll
    for (int i = 0; i < 16; ++i) { hreg0[i] = 0.f; hreg1[i] = 0.f; }

    WSet W0, W1;
    load_h_side(W0, eWhh0, ebih0, ebhh0, jA, j4, quad);
    load_h_side(W1, eWhh1, ebih1, ebhh1, jA, j4, quad);
    load_x_side(W1, eWih1, jA, quad);
    {
        f32x4 xw[6];
        #pragma unroll
        for (int rg = 0; rg < 4; ++rg) {
            xw[0][rg] = eWih0[(j4 + rg) * 2];        xw[1][rg] = eWih0[(j4 + rg) * 2 + 1];
            xw[2][rg] = eWih0[(64 + j4 + rg) * 2];   xw[3][rg] = eWih0[(64 + j4 + rg) * 2 + 1];
            xw[4][rg] = eWih0[(128 + j4 + rg) * 2];  xw[5][rg] = eWih0[(128 + j4 + rg) * 2 + 1];
        }
        int c0 = 0, c1 = 0;
        __syncthreads();

        // ---------------- encoder: 1 barrier per pair ----------------
        #pragma unroll 1
        for (int t = 0; t < T_SEQ; ++t) {
            float2 xv[4];
            #pragma unroll
            for (int mt = 0; mt < 4; ++mt) xv[mt] = xe[t * 64 + mt * 16 + col];
            cell<false>(W0, hbuf[0], hbuf[c0], hbuf[c0 ^ 1], hreg0, xw, xv, ro0, ro1, wo);
            c0 ^= 1; __syncthreads();
            cell<true>(W1, hbuf[c0], hbuf[2 + c1], hbuf[2 + (c1 ^ 1)], hreg1, nullptr, nullptr, ro0, ro1, wo);
            c1 ^= 1;
        }
    }
    // encoder used odd T_SEQ=11 -> c0=1, c1=1 now
    int c0 = 1, c1 = 1;

    // ---------------- phase switch ----------------
    load_h_side(W0, dWhh0, dbih0, dbhh0, jA, j4, quad);
    #pragma unroll
    for (int ks = 0; ks < 2; ++ks) {
        const int k0 = ks * 32 + quad * 8;
        W0.xR[ks] = cfrag(dWih0, fcW, jA,       k0);
        W0.xZ[ks] = cfrag(dWih0, fcW, jA + 64,  k0);
        W0.xN[ks] = cfrag(dWih0, fcW, jA + 128, k0);
    }
    #pragma unroll
    for (int rg = 0; rg < 4; ++rg) {   // fold fc_b through Wih0 into gi biases
        const int j = j4 + rg;
        W0.bR[rg]  += dWih0[j * 2] * fcb[0]         + dWih0[j * 2 + 1] * fcb[1];
        W0.bZ[rg]  += dWih0[(64 + j) * 2] * fcb[0]  + dWih0[(64 + j) * 2 + 1] * fcb[1];
        W0.bNi[rg] += dWih0[(128 + j) * 2] * fcb[0] + dWih0[(128 + j) * 2 + 1] * fcb[1];
    }
    load_h_side(W1, dWhh1, dbih1, dbhh1, jA, j4, quad);
    load_x_side(W1, dWih1, jA, quad);
    f16x8 fcf[2];
    #pragma unroll
    for (int ks = 0; ks < 2; ++ks) {
        #pragma unroll
        for (int i = 0; i < 8; ++i) fcf[ks][i] = (f16)0.f;
        if (col < 2) fcf[ks] = wfrag(fcW, col, ks * 32 + quad * 8);
    }
    f32x4 pb;
    #pragma unroll
    for (int rg = 0; rg < 4; ++rg) pb[rg] = (quad == 0 && rg < 2) ? fcb[rg] : 0.f;

    float* __restrict__ outp = out + (size_t)r0 * (STEPS * 2);

    // ---------------- decoder step 0 (peeled: kills xw/xv live ranges) ----------------
    {
        f32x4 xw[6];
        #pragma unroll
        for (int rg = 0; rg < 4; ++rg) {   // x-path weights for decoder step 0 only
            xw[0][rg] = dWih0[(j4 + rg) * 2];        xw[1][rg] = dWih0[(j4 + rg) * 2 + 1];
            xw[2][rg] = dWih0[(64 + j4 + rg) * 2];   xw[3][rg] = dWih0[(64 + j4 + rg) * 2 + 1];
            xw[4][rg] = dWih0[(128 + j4 + rg) * 2];  xw[5][rg] = dWih0[(128 + j4 + rg) * 2 + 1];
        }
        float2 xv0[4];
        #pragma unroll
        for (int mt = 0; mt < 4; ++mt) xv0[mt] = xe[(T_SEQ - 1) * 64 + mt * 16 + col];
        cell<false>(W0, hbuf[0], hbuf[c0], hbuf[c0 ^ 1], hreg0, xw, xv0, ro0, ro1, wo);
        c0 ^= 1; __syncthreads();
        cell<true>(W1, hbuf[c0], hbuf[2 + c1], hbuf[2 + (c1 ^ 1)], hreg1, nullptr, nullptr, ro0, ro1, wo);
        c1 ^= 1; __syncthreads();
        f16x8 hb0 = *(const f16x8*)(hbuf[2 + c1] + ro0 + w * 1024);
        f16x8 hb1 = *(const f16x8*)(hbuf[2 + c1] + ro1 + w * 1024);
        f32x4 p = pb;
        p = mfma16(fcf[0], hb0, p);
        p = mfma16(fcf[1], hb1, p);
        if (quad == 0)
            *(float2*)&outp[(size_t)(w * 16 + col) * (STEPS * 2)] = make_float2(p[0], p[1]);
    }

    // ---------------- decoder steps 1..79: uniform body, 2 barriers ----------------
    #pragma unroll 1
    for (int s = 1; s < STEPS; ++s) {
        cell<true>(W0, hbuf[2 + c1], hbuf[c0], hbuf[c0 ^ 1], hreg0, nullptr, nullptr, ro0, ro1, wo);
        c0 ^= 1; __syncthreads();
        cell<true>(W1, hbuf[c0], hbuf[2 + c1], hbuf[2 + (c1 ^ 1)], hreg1, nullptr, nullptr, ro0, ro1, wo);
        c1 ^= 1; __syncthreads();

        // FC head on the fresh h1 (wave w covers rows 16w..16w+15)
        f16x8 hb0 = *(const f16x8*)(hbuf[2 + c1] + ro0 + w * 1024);
        f16x8 hb1 = *(const f16x8*)(hbuf[2 + c1] + ro1 + w * 1024);
        f32x4 p = pb;
        p = mfma16(fcf[0], hb0, p);
        p = mfma16(fcf[1], hb1, p);
        if (quad == 0) {
            *(float2*)&outp[(size_t)(w * 16 + col) * (STEPS * 2) + s * 2] =
                make_float2(p[0], p[1]);
        }
    }
}

extern "C" void kernel_launch(void* const* d_in, const int* in_sizes, int n_in,
                              void* d_out, int out_size, void* d_ws, size_t ws_size,
                              hipStream_t stream) {
    (void)n_in; (void)out_size; (void)d_ws; (void)ws_size;

    const float* x     = (const float*)d_in[0];
    const float* eWih0 = (const float*)d_in[1];
    const float* eWhh0 = (const float*)d_in[2];
    const float* ebih0 = (const float*)d_in[3];
    const float* ebhh0 = (const float*)d_in[4];
    const float* eWih1 = (const float*)d_in[5];
    const float* eWhh1 = (const float*)d_in[6];
    const float* ebih1 = (const float*)d_in[7];
    const float* ebhh1 = (const float*)d_in[8];
    const float* dWih0 = (const float*)d_in[9];
    const float* dWhh0 = (const float*)d_in[10];
    const float* dbih0 = (const float*)d_in[11];
    const float* dbhh0 = (const float*)d_in[12];
    const float* dWih1 = (const float*)d_in[13];
    const float* dWhh1 = (const float*)d_in[14];
    const float* dbih1 = (const float*)d_in[15];
    const float* dbhh1 = (const float*)d_in[16];
    const float* fcW   = (const float*)d_in[17];
    const float* fcb   = (const float*)d_in[18];
    float* out = (float*)d_out;

    const int b = in_sizes[0] / (T_SEQ * 2);   // 32768
    dim3 grid(b / 64), block(256);
    hipLaunchKernelGGL(gru_traj_mfma3, grid, block, 0, stream,
        x, eWih0, eWhh0, ebih0, ebhh0, eWih1, eWhh1, ebih1, ebhh1,
        dWih0, dWhh0, dbih0, dbhh0, dWih1, dWhh1, dbih1, dbhh1,
        fcW, fcb, out);
}

// Round 7
// 771.271 us; speedup vs baseline: 1.1784x; 1.1784x over previous
//
#include <hip/hip_runtime.h>
#include <cstddef>

#define T_SEQ 11
#define STEPS 80

typedef _Float16 f16;
typedef _Float16 f16x4 __attribute__((ext_vector_type(4)));
typedef _Float16 f16x8 __attribute__((ext_vector_type(8)));
typedef float    f32x4 __attribute__((ext_vector_type(4)));

__device__ __forceinline__ f32x4 mfma16(f16x8 a, f16x8 b, f32x4 c) {
    return __builtin_amdgcn_mfma_f32_16x16x32_f16(a, b, c, 0, 0, 0);
}
__device__ __forceinline__ float sig1(float x) {
    return __fdividef(1.f, 1.f + __expf(-x));
}
__device__ __forceinline__ float th1(float x) {
    return 1.f - __fdividef(2.f, __expf(2.f * x) + 1.f);
}

// A-frag: lane holds W[row][k0..k0+7] (m = lane&15 selects row within tile).
__device__ __forceinline__ f16x8 wfrag(const float* __restrict__ W, int row, int k0) {
    f16x8 r;
    #pragma unroll
    for (int i = 0; i < 8; ++i) r[i] = (f16)W[row * 64 + k0 + i];
    return r;
}
// Composed decoder-l0 gi weights: Wcomb[g][k] = Wih0[g][0]*fcW[0][k] + Wih0[g][1]*fcW[1][k]
__device__ __forceinline__ f16x8 cfrag(const float* __restrict__ Wih0,
                                       const float* __restrict__ fcW, int row, int k0) {
    f16x8 r;
    #pragma unroll
    for (int i = 0; i < 8; ++i)
        r[i] = (f16)(Wih0[row * 2] * fcW[k0 + i] + Wih0[row * 2 + 1] * fcW[64 + k0 + i]);
    return r;
}

struct WSet {
    f16x8 xR[2], xZ[2], xN[2];   // gi-source weights (MFMA path)
    f16x8 hR[2], hZ[2], hN[2];   // recurrent weights
    f32x4 bR, bZ, bNi, bNh;      // biases, vector over rg (j = j4+rg)
};

__device__ __forceinline__ void load_h_side(WSet& W,
    const float* __restrict__ Whh, const float* __restrict__ bih,
    const float* __restrict__ bhh, int jA, int j4, int quad)
{
    #pragma unroll
    for (int ks = 0; ks < 2; ++ks) {
        const int k0 = ks * 32 + quad * 8;
        W.hR[ks] = wfrag(Whh, jA,       k0);
        W.hZ[ks] = wfrag(Whh, jA + 64,  k0);
        W.hN[ks] = wfrag(Whh, jA + 128, k0);
    }
    #pragma unroll
    for (int rg = 0; rg < 4; ++rg) {
        W.bR[rg]  = bih[j4 + rg] + bhh[j4 + rg];
        W.bZ[rg]  = bih[64 + j4 + rg] + bhh[64 + j4 + rg];
        W.bNi[rg] = bih[128 + j4 + rg];
        W.bNh[rg] = bhh[128 + j4 + rg];
    }
}
__device__ __forceinline__ void load_x_side(WSet& W, const float* __restrict__ Wx,
                                            int jA, int quad)
{
    #pragma unroll
    for (int ks = 0; ks < 2; ++ks) {
        const int k0 = ks * 32 + quad * 8;
        W.xR[ks] = wfrag(Wx, jA,       k0);
        W.xZ[ks] = wfrag(Wx, jA + 64,  k0);
        W.xN[ks] = wfrag(Wx, jA + 128, k0);
    }
}

// One GRU cell, D[j][row] orientation. Reads B-frags (h) from swizzled LDS,
// writes new h (f16x4 per row-tile) to Dst.
// fp32 h-master lives in thread-private LDS (hm): each (j,row) slot is touched
// by exactly one thread for the whole kernel -> no sync needed, no register
// cost. This replaces the 32-VGPR hreg master that pushed us over the 256-reg
// budget at 2 waves/SIMD (round 5: compiler spill to scratch; round 6: 1
// wave/SIMD occupancy loss).
template<bool XM>
__device__ __forceinline__ void cell(const WSet& W,
    const f16* __restrict__ Xs, const f16* __restrict__ Hs, f16* __restrict__ Dst,
    float2* __restrict__ hm, int tid,
    const f32x4* __restrict__ xw, const float2* __restrict__ xv,
    int ro0, int ro1, int wo)
{
    #pragma unroll
    for (int mt = 0; mt < 4; ++mt) {
        f32x4 aR = W.bR, aZ = W.bZ, aNi = W.bNi, aNh = W.bNh;
        const int mo = mt * 1024;
        f16x8 hb0 = *(const f16x8*)(Hs + ro0 + mo);
        f16x8 hb1 = *(const f16x8*)(Hs + ro1 + mo);
        aR  = mfma16(W.hR[0], hb0, aR);  aR  = mfma16(W.hR[1], hb1, aR);
        aZ  = mfma16(W.hZ[0], hb0, aZ);  aZ  = mfma16(W.hZ[1], hb1, aZ);
        aNh = mfma16(W.hN[0], hb0, aNh); aNh = mfma16(W.hN[1], hb1, aNh);
        if constexpr (XM) {
            f16x8 xb0 = *(const f16x8*)(Xs + ro0 + mo);
            f16x8 xb1 = *(const f16x8*)(Xs + ro1 + mo);
            aR  = mfma16(W.xR[0], xb0, aR);  aR  = mfma16(W.xR[1], xb1, aR);
            aZ  = mfma16(W.xZ[0], xb0, aZ);  aZ  = mfma16(W.xZ[1], xb1, aZ);
            aNi = mfma16(W.xN[0], xb0, aNi); aNi = mfma16(W.xN[1], xb1, aNi);
        } else {
            const float x0 = xv[mt].x, x1 = xv[mt].y;
            aR  += x0 * xw[0] + x1 * xw[1];
            aZ  += x0 * xw[2] + x1 * xw[3];
            aNi += x0 * xw[4] + x1 * xw[5];
        }
        float2 ho01 = hm[(mt * 2 + 0) * 256 + tid];
        float2 ho23 = hm[(mt * 2 + 1) * 256 + tid];
        const float ho[4] = {ho01.x, ho01.y, ho23.x, ho23.y};
        float hn[4];
        f16x4 o;
        #pragma unroll
        for (int i = 0; i < 4; ++i) {
            const float r = sig1(aR[i]);
            const float z = sig1(aZ[i]);
            const float n = th1(aNi[i] + r * aNh[i]);
            const float h = n + z * (ho[i] - n);
            hn[i] = h;
            o[i] = (f16)h;
        }
        hm[(mt * 2 + 0) * 256 + tid] = make_float2(hn[0], hn[1]);
        hm[(mt * 2 + 1) * 256 + tid] = make_float2(hn[2], hn[3]);
        *(f16x4*)(Dst + wo + mo) = o;   // one ds_write_b64, swizzle-aligned
    }
}

__global__ __launch_bounds__(256, 2)
void gru_traj_mfma4(
    const float* __restrict__ x,
    const float* __restrict__ eWih0, const float* __restrict__ eWhh0,
    const float* __restrict__ ebih0, const float* __restrict__ ebhh0,
    const float* __restrict__ eWih1, const float* __restrict__ eWhh1,
    const float* __restrict__ ebih1, const float* __restrict__ ebhh1,
    const float* __restrict__ dWih0, const float* __restrict__ dWhh0,
    const float* __restrict__ dbih0, const float* __restrict__ dbhh0,
    const float* __restrict__ dWih1, const float* __restrict__ dWhh1,
    const float* __restrict__ dbih1, const float* __restrict__ dbhh1,
    const float* __restrict__ fcW,  const float* __restrict__ fcb,
    float* __restrict__ out)
{
    // 4 f16 h buffers (double-buffered per layer, MFMA operands), XOR-swizzled.
    __shared__ f16 hbuf[4][64 * 64];     // [0,1]=h0, [2,3]=h1   (32 KB)
    __shared__ float2 hm0[8 * 256];      // fp32 h0 master, thread-private (16 KB)
    __shared__ float2 hm1[8 * 256];      // fp32 h1 master, thread-private (16 KB)
    __shared__ float2 xe[T_SEQ * 64];    // [t][row] -> broadcast reads (5.5 KB)

    const int tid  = threadIdx.x;
    const int lane = tid & 63;
    const int w    = __builtin_amdgcn_readfirstlane(tid >> 6);
    const int quad = lane >> 4;
    const int col  = lane & 15;
    const int r0   = blockIdx.x * 64;

    for (int i = tid; i < T_SEQ * 64; i += 256) {
        const int t = i >> 6, r = i & 63;
        xe[i] = ((const float2*)x)[(size_t)(r0 + r) * T_SEQ + t];
    }
    for (int i = tid; i < 64 * 64; i += 256) { hbuf[0][i] = (f16)0.f; hbuf[2][i] = (f16)0.f; }
    #pragma unroll
    for (int p = 0; p < 8; ++p) {
        hm0[p * 256 + tid] = make_float2(0.f, 0.f);
        hm1[p * 256 + tid] = make_float2(0.f, 0.f);
    }

    // Swizzled offsets (halves): phys(row,k) = row*64 + (((k>>3)^(row&7))<<3) + (k&7)
    const int c7  = col & 7;
    const int ro0 = col * 64 + ((quad ^ c7) << 3);             // B-frag read, ks=0
    const int ro1 = col * 64 + (((4 + quad) ^ c7) << 3);       // B-frag read, ks=1
    const int wo  = col * 64 + ((((w << 1) | (quad >> 1)) ^ c7) << 3) + ((quad & 1) << 2);

    const int jA = w * 16 + col;        // A-frag W-row base (m = col)
    const int j4 = w * 16 + quad * 4;   // epilogue/bias j base (m = quad*4+rg)

    WSet W0, W1;
    load_h_side(W0, eWhh0, ebih0, ebhh0, jA, j4, quad);
    load_h_side(W1, eWhh1, ebih1, ebhh1, jA, j4, quad);
    load_x_side(W1, eWih1, jA, quad);
    {
        f32x4 xw[6];
        #pragma unroll
        for (int rg = 0; rg < 4; ++rg) {
            xw[0][rg] = eWih0[(j4 + rg) * 2];        xw[1][rg] = eWih0[(j4 + rg) * 2 + 1];
            xw[2][rg] = eWih0[(64 + j4 + rg) * 2];   xw[3][rg] = eWih0[(64 + j4 + rg) * 2 + 1];
            xw[4][rg] = eWih0[(128 + j4 + rg) * 2];  xw[5][rg] = eWih0[(128 + j4 + rg) * 2 + 1];
        }
        int c0 = 0, c1 = 0;
        __syncthreads();

        // ---------------- encoder: 1 barrier per pair ----------------
        #pragma unroll 1
        for (int t = 0; t < T_SEQ; ++t) {
            float2 xv[4];
            #pragma unroll
            for (int mt = 0; mt < 4; ++mt) xv[mt] = xe[t * 64 + mt * 16 + col];
            cell<false>(W0, hbuf[0], hbuf[c0], hbuf[c0 ^ 1], hm0, tid, xw, xv, ro0, ro1, wo);
            c0 ^= 1; __syncthreads();
            cell<true>(W1, hbuf[c0], hbuf[2 + c1], hbuf[2 + (c1 ^ 1)], hm1, tid, nullptr, nullptr, ro0, ro1, wo);
            c1 ^= 1;
        }
    }
    // encoder ran odd T_SEQ=11 -> c0=1, c1=1 now
    int c0 = 1, c1 = 1;

    // ---------------- phase switch ----------------
    load_h_side(W0, dWhh0, dbih0, dbhh0, jA, j4, quad);
    #pragma unroll
    for (int ks = 0; ks < 2; ++ks) {
        const int k0 = ks * 32 + quad * 8;
        W0.xR[ks] = cfrag(dWih0, fcW, jA,       k0);
        W0.xZ[ks] = cfrag(dWih0, fcW, jA + 64,  k0);
        W0.xN[ks] = cfrag(dWih0, fcW, jA + 128, k0);
    }
    #pragma unroll
    for (int rg = 0; rg < 4; ++rg) {   // fold fc_b through Wih0 into gi biases
        const int j = j4 + rg;
        W0.bR[rg]  += dWih0[j * 2] * fcb[0]         + dWih0[j * 2 + 1] * fcb[1];
        W0.bZ[rg]  += dWih0[(64 + j) * 2] * fcb[0]  + dWih0[(64 + j) * 2 + 1] * fcb[1];
        W0.bNi[rg] += dWih0[(128 + j) * 2] * fcb[0] + dWih0[(128 + j) * 2 + 1] * fcb[1];
    }
    load_h_side(W1, dWhh1, dbih1, dbhh1, jA, j4, quad);
    load_x_side(W1, dWih1, jA, quad);
    f16x8 fcf[2];
    #pragma unroll
    for (int ks = 0; ks < 2; ++ks) {
        #pragma unroll
        for (int i = 0; i < 8; ++i) fcf[ks][i] = (f16)0.f;
        if (col < 2) fcf[ks] = wfrag(fcW, col, ks * 32 + quad * 8);
    }
    f32x4 pb;
    #pragma unroll
    for (int rg = 0; rg < 4; ++rg) pb[rg] = (quad == 0 && rg < 2) ? fcb[rg] : 0.f;

    float* __restrict__ outp = out + (size_t)r0 * (STEPS * 2);

    // ---------------- decoder step 0 (peeled: kills xw/xv live ranges) ----------------
    {
        f32x4 xw[6];
        #pragma unroll
        for (int rg = 0; rg < 4; ++rg) {   // x-path weights for decoder step 0 only
            xw[0][rg] = dWih0[(j4 + rg) * 2];        xw[1][rg] = dWih0[(j4 + rg) * 2 + 1];
            xw[2][rg] = dWih0[(64 + j4 + rg) * 2];   xw[3][rg] = dWih0[(64 + j4 + rg) * 2 + 1];
            xw[4][rg] = dWih0[(128 + j4 + rg) * 2];  xw[5][rg] = dWih0[(128 + j4 + rg) * 2 + 1];
        }
        float2 xv0[4];
        #pragma unroll
        for (int mt = 0; mt < 4; ++mt) xv0[mt] = xe[(T_SEQ - 1) * 64 + mt * 16 + col];
        cell<false>(W0, hbuf[0], hbuf[c0], hbuf[c0 ^ 1], hm0, tid, xw, xv0, ro0, ro1, wo);
        c0 ^= 1; __syncthreads();
        cell<true>(W1, hbuf[c0], hbuf[2 + c1], hbuf[2 + (c1 ^ 1)], hm1, tid, nullptr, nullptr, ro0, ro1, wo);
        c1 ^= 1; __syncthreads();
        f16x8 hb0 = *(const f16x8*)(hbuf[2 + c1] + ro0 + w * 1024);
        f16x8 hb1 = *(const f16x8*)(hbuf[2 + c1] + ro1 + w * 1024);
        f32x4 p = pb;
        p = mfma16(fcf[0], hb0, p);
        p = mfma16(fcf[1], hb1, p);
        if (quad == 0)
            *(float2*)&outp[(size_t)(w * 16 + col) * (STEPS * 2)] = make_float2(p[0], p[1]);
    }

    // ---------------- decoder steps 1..79: uniform body, 2 barriers ----------------
    #pragma unroll 1
    for (int s = 1; s < STEPS; ++s) {
        cell<true>(W0, hbuf[2 + c1], hbuf[c0], hbuf[c0 ^ 1], hm0, tid, nullptr, nullptr, ro0, ro1, wo);
        c0 ^= 1; __syncthreads();
        cell<true>(W1, hbuf[c0], hbuf[2 + c1], hbuf[2 + (c1 ^ 1)], hm1, tid, nullptr, nullptr, ro0, ro1, wo);
        c1 ^= 1; __syncthreads();

        // FC head on the fresh h1 (wave w covers rows 16w..16w+15)
        f16x8 hb0 = *(const f16x8*)(hbuf[2 + c1] + ro0 + w * 1024);
        f16x8 hb1 = *(const f16x8*)(hbuf[2 + c1] + ro1 + w * 1024);
        f32x4 p = pb;
        p = mfma16(fcf[0], hb0, p);
        p = mfma16(fcf[1], hb1, p);
        if (quad == 0) {
            *(float2*)&outp[(size_t)(w * 16 + col) * (STEPS * 2) + s * 2] =
                make_float2(p[0], p[1]);
        }
    }
}

extern "C" void kernel_launch(void* const* d_in, const int* in_sizes, int n_in,
                              void* d_out, int out_size, void* d_ws, size_t ws_size,
                              hipStream_t stream) {
    (void)n_in; (void)out_size; (void)d_ws; (void)ws_size;

    const float* x     = (const float*)d_in[0];
    const float* eWih0 = (const float*)d_in[1];
    const float* eWhh0 = (const float*)d_in[2];
    const float* ebih0 = (const float*)d_in[3];
    const float* ebhh0 = (const float*)d_in[4];
    const float* eWih1 = (const float*)d_in[5];
    const float* eWhh1 = (const float*)d_in[6];
    const float* ebih1 = (const float*)d_in[7];
    const float* ebhh1 = (const float*)d_in[8];
    const float* dWih0 = (const float*)d_in[9];
    const float* dWhh0 = (const float*)d_in[10];
    const float* dbih0 = (const float*)d_in[11];
    const float* dbhh0 = (const float*)d_in[12];
    const float* dWih1 = (const float*)d_in[13];
    const float* dWhh1 = (const float*)d_in[14];
    const float* dbih1 = (const float*)d_in[15];
    const float* dbhh1 = (const float*)d_in[16];
    const float* fcW   = (const float*)d_in[17];
    const float* fcb   = (const float*)d_in[18];
    float* out = (float*)d_out;

    const int b = in_sizes[0] / (T_SEQ * 2);   // 32768
    dim3 grid(b / 64), block(256);
    hipLaunchKernelGGL(gru_traj_mfma4, grid, block, 0, stream,
        x, eWih0, eWhh0, ebih0, ebhh0, eWih1, eWhh1, ebih1, ebhh1,
        dWih0, dWhh0, dbih0, dbhh0, dWih1, dWhh1, dbih1, dbhh1,
        fcW, fcb, out);
}